// Round 12
// baseline (249.119 us; speedup 1.0000x reference)
//
#include <hip/hip_runtime.h>
#include <stdint.h>

#define Q_IN 33152
#define NTILES 1160   // 8 chunks x 145 tiles (1 linear + 144 quad)
#define TPC 145

typedef _Float16 half8 __attribute__((ext_vector_type(8)));
typedef float floatx4 __attribute__((ext_vector_type(4)));
typedef uint32_t uint4v __attribute__((ext_vector_type(4)));

// ---------------------------------------------------------------------------
// Tile table in EXECUTION order, chunk-major: T = kch*145 + tt.
// tt=0: linear segment (i0=-1, jb=32*kch). tt>=1: quad tile Q = kch*144+tt-1,
// group-major (g, jt) with jb = 32*(g+jt), inner s=0..31, i0 = 32g+s.
__global__ void build_tab(uint32_t* tab) {
  int T = blockIdx.x * 256 + threadIdx.x;
  if (T >= NTILES) return;
  int kch = T / TPC, tt = T % TPC;
  int i0, jb;
  if (tt == 0) { i0 = -1; jb = 32 * kch; }
  else {
    int Q = kch * 144 + (tt - 1);
    int grp = Q >> 5, s = Q & 31;
    int g = 0, base = 0;
    for (; g < 8; ++g) { int cnt = 8 - g; if (grp < base + cnt) break; base += cnt; }
    int jt = grp - base;
    i0 = 32 * g + s;
    jb = 32 * (g + jt);
  }
  tab[T] = (((uint32_t)(uint16_t)(short)i0) << 16) | (uint32_t)(uint16_t)jb;
}

// ---------------------------------------------------------------------------
// W (f32 [Oreal x Q_IN]) -> f16 16x16-fragment-tiled Wt (proven layout).
__global__ void convert_w(const float* __restrict__ W, _Float16* __restrict__ Wt,
                          const uint32_t* __restrict__ tab, int NTT, int Oreal) {
  int tid = blockIdx.x * 256 + threadIdx.x;
  if (tid >= NTILES * NTT * 64) return;
  int l = tid & 63;
  int nt = (tid >> 6) % NTT;
  int T = tid / (64 * NTT);
  int o = nt * 16 + (l & 15);
  int koff = (l >> 4) * 8;
  half8 v;
#pragma unroll
  for (int t = 0; t < 8; ++t) v[t] = (_Float16)0.f;
  if (o < Oreal) {
    uint32_t e = tab[T];
    int i0 = (short)(e >> 16);
    int jb = (int)(e & 0xFFFFu);
    const float* row = W + (size_t)o * Q_IN;
    if (i0 < 0) {
#pragma unroll
      for (int t = 0; t < 8; ++t) v[t] = (_Float16)row[jb + koff + t];
    } else {
      int qb = 256 + i0 * 256 - (i0 * (i0 - 1)) / 2 - i0;  // q = qb + j
#pragma unroll
      for (int t = 0; t < 8; ++t) {
        int j = jb + koff + t;
        if (j >= i0) v[t] = (_Float16)row[qb + j];
      }
    }
  }
  *(half8*)(Wt + (size_t)(T * NTT + nt) * 512 + l * 8) = v;
}

// ---------------------------------------------------------------------------
// reduce partials + bias -> h  (4096 x 256 f32), float4 vectorized
__global__ void reduce_h(const float* __restrict__ part, const float* __restrict__ bias,
                         float* __restrict__ h) {
  int t = blockIdx.x * 256 + threadIdx.x;     // 262144 threads, 1 float4 each
  float4 acc = *(const float4*)(bias + ((t & 63) << 2));
#pragma unroll
  for (int k = 0; k < 8; ++k) {
    float4 p = *(const float4*)(part + (size_t)k * 1048576 + t * 4);
    acc.x += p.x; acc.y += p.y; acc.z += p.z; acc.w += p.w;
  }
  *(float4*)(h + t * 4) = acc;
}

// reduce partials + bias -> out (4096 x 10), part2 stride 16
__global__ void reduce_out(const float* __restrict__ part2, const float* __restrict__ b2,
                           float* __restrict__ out) {
  int t = blockIdx.x * 256 + threadIdx.x;     // 40960
  if (t >= 40960) return;
  int b = t / 10, o = t - b * 10;
  float acc = b2[o];
#pragma unroll
  for (int k = 0; k < 8; ++k) acc += part2[(size_t)k * 65536 + b * 16 + o];
  out[t] = acc;
}

__device__ inline floatx4 mfma16(half8 a, half8 b, floatx4 c) {
  return __builtin_amdgcn_mfma_f32_16x16x32_f16(a, b, c, 0, 0, 0);
}

// a * broadcast(lo/hi half of s) via v_pk_mul_f16 op_sel (R9-proven)
__device__ inline half8 splat_mul_lo(half8 a, uint32_t s) {
  uint4v av = __builtin_bit_cast(uint4v, a), r;
#pragma unroll
  for (int k = 0; k < 4; ++k)
    asm("v_pk_mul_f16 %0, %1, %2 op_sel:[0,0] op_sel_hi:[1,0]"
        : "=v"(r[k]) : "v"(av[k]), "v"(s));
  return __builtin_bit_cast(half8, r);
}
__device__ inline half8 splat_mul_hi(half8 a, uint32_t s) {
  uint4v av = __builtin_bit_cast(uint4v, a), r;
#pragma unroll
  for (int k = 0; k < 4; ++k)
    asm("v_pk_mul_f16 %0, %1, %2 op_sel:[0,1] op_sel_hi:[1,1]"
        : "=v"(r[k]) : "v"(av[k]), "v"(s));
  return __builtin_bit_cast(half8, r);
}

// ---------------------------------------------------------------------------
// Main quadratic GEMM (layers 0/1), 16x16x32 MFMA (R9-proven math), wave
// split 2M x 4N: per-wave 64x64 (MT=4, NTW=4). Each scaled A-octet feeds 4
// MFMAs -> 16 pk_mul/tile/wave (was 32). B global->reg in two 2-tile groups,
// 4 phases per 8-tile block, consume-then-refill. No barriers in K-loop.
__global__ __launch_bounds__(512, 1) void qgemm_main(
    const float* __restrict__ hIn, const _Float16* __restrict__ Wt,
    float* __restrict__ part, const uint32_t* __restrict__ gtab) {
  __shared__ _Float16 hT[128 * 256];     // 64 KB, 512 B/row, XOR-swizzled cols

  const int tid = threadIdx.x;
  const int l = tid & 63;
  const int wid = tid >> 6;
  const int wm = wid >> 2;         // row half (64 rows)
  const int wn = wid & 3;          // col quarter (64 cols = 4 n-tiles)
  const int kch = blockIdx.x & 7;  // same-chunk WGs share an XCD (L2-resident Wt)
  const int rb = blockIdx.x >> 3;
  const int tbase = kch * TPC;

  const char* gb = (const char*)Wt + (size_t)tbase * 16384;
  const char* gq = gb + 16384;           // quad tiles start
  const uint32_t lo = (uint32_t)(wn * 4096 + l * 16);

  // linear-tile B (4 n-tiles for this wave)
  half8 blin[4];
#pragma unroll
  for (int j = 0; j < 4; ++j)
    blin[j] = *(const half8*)(gb + (lo + j * 1024u));

  half8 G0[2][4], G1[2][4];              // [t2][nt], 2-tile groups
  auto issueG0 = [&](uint32_t qt) {
#pragma unroll
    for (int t2 = 0; t2 < 2; ++t2)
#pragma unroll
      for (int j = 0; j < 4; ++j)
        G0[t2][j] = *(const half8*)(gq + (lo + (qt + t2) * 16384u + j * 1024u));
  };
  auto issueG1 = [&](uint32_t qt) {
#pragma unroll
    for (int t2 = 0; t2 < 2; ++t2)
#pragma unroll
      for (int j = 0; j < 4; ++j)
        G1[t2][j] = *(const half8*)(gq + (lo + (qt + t2) * 16384u + j * 1024u));
  };
  issueG0(0);
  issueG1(2);

  // ---- stage h tile (f32 -> f16, swizzle byte^=(row&7)<<4; R9-exact) ----
  {
    int r = tid >> 2, sg = tid & 3;
    const float* src = hIn + (size_t)(rb * 128 + r) * 256 + sg * 64;
    char* dst = (char*)hT + r * 512;
    int xo = (r & 7) << 4;
#pragma unroll
    for (int oc = 0; oc < 8; ++oc) {
      float4 f0 = *(const float4*)(src + oc * 8);
      float4 f1 = *(const float4*)(src + oc * 8 + 4);
      half8 hv;
      hv[0] = (_Float16)f0.x; hv[1] = (_Float16)f0.y;
      hv[2] = (_Float16)f0.z; hv[3] = (_Float16)f0.w;
      hv[4] = (_Float16)f1.x; hv[5] = (_Float16)f1.y;
      hv[6] = (_Float16)f1.z; hv[7] = (_Float16)f1.w;
      *(half8*)(dst + ((sg * 128 + oc * 16) ^ xo)) = hv;
    }
  }
  __syncthreads();

  floatx4 acc[4][4];
#pragma unroll
  for (int mt = 0; mt < 4; ++mt)
#pragma unroll
    for (int nt = 0; nt < 4; ++nt)
#pragma unroll
      for (int rg = 0; rg < 4; ++rg) acc[mt][nt][rg] = 0.f;

  int rowb[4];
#pragma unroll
  for (int mt = 0; mt < 4; ++mt)
    rowb[mt] = (wm * 64 + mt * 16 + (l & 15)) * 512;
  const int xorb = (l & 7) << 4;
  const int koffA = (l >> 4) * 16;
  const char* hTb = (const char*)hT;

  half8 a[4];
  uint4v scu[4];
  int prevjb;

  auto loadA = [&](int jb) {
#pragma unroll
    for (int mt = 0; mt < 4; ++mt)
      a[mt] = *(const half8*)(hTb + rowb[mt] + ((jb * 2 + koffA) ^ xorb));
  };
  auto consumeG0 = [&](const int t2, const int s) {
#pragma unroll
    for (int mt = 0; mt < 4; ++mt) {
      uint32_t sd = scu[mt][s >> 1];
      half8 as_ = (s & 1) ? splat_mul_hi(a[mt], sd) : splat_mul_lo(a[mt], sd);
#pragma unroll
      for (int j = 0; j < 4; ++j)
        acc[mt][j] = mfma16(as_, G0[t2][j], acc[mt][j]);
    }
  };
  auto consumeG1 = [&](const int t2, const int s) {
#pragma unroll
    for (int mt = 0; mt < 4; ++mt) {
      uint32_t sd = scu[mt][s >> 1];
      half8 as_ = (s & 1) ? splat_mul_hi(a[mt], sd) : splat_mul_lo(a[mt], sd);
#pragma unroll
      for (int j = 0; j < 4; ++j)
        acc[mt][j] = mfma16(as_, G1[t2][j], acc[mt][j]);
    }
  };

  // ---- tile 0: linear (scale = 1) ----
  {
    uint32_t e0 = gtab[tbase];
    int jb = (int)(e0 & 0xFFFFu);
    loadA(jb);
#pragma unroll
    for (int mt = 0; mt < 4; ++mt)
#pragma unroll
      for (int j = 0; j < 4; ++j)
        acc[mt][j] = mfma16(a[mt], blin[j], acc[mt][j]);
    prevjb = jb;
  }

  // ---- 18 blocks of 8 quad tiles; 4 phases of 2 tiles each ----
  uint32_t qt = 0;
  for (int blk = 0; blk < 18; ++blk) {
    uint32_t e = gtab[tbase + 1 + blk * 8];
    int i0b = (int)(e >> 16);        // block-start i0 (multiple of 8)
    int jb = (int)(e & 0xFFFFu);
#pragma unroll
    for (int mt = 0; mt < 4; ++mt)
      scu[mt] = *(const uint4v*)(hTb + rowb[mt] + ((i0b * 2) ^ xorb));
    if (jb != prevjb) { prevjb = jb; loadA(jb); }

    consumeG0(0, 0); consumeG0(1, 1); issueG0(qt + 4);
    consumeG1(0, 2); consumeG1(1, 3); issueG1(qt + 6);
    consumeG0(0, 4); consumeG0(1, 5); if (blk < 17) issueG0(qt + 8);
    consumeG1(0, 6); consumeG1(1, 7); if (blk < 17) issueG1(qt + 10);
    qt += 8;
  }

  // ---- epilogue: plain stores (16x16 C/D: col=l&15, row=(l>>4)*4+rg) ----
  float* op = part + (size_t)kch * 1048576;
#pragma unroll
  for (int mt = 0; mt < 4; ++mt) {
    int rbase = rb * 128 + wm * 64 + mt * 16 + (l >> 4) * 4;
#pragma unroll
    for (int nt = 0; nt < 4; ++nt) {
      int c = wn * 64 + nt * 16 + (l & 15);
#pragma unroll
      for (int rg = 0; rg < 4; ++rg)
        op[(size_t)(rbase + rg) * 256 + c] = acc[mt][nt][rg];
    }
  }
}

// ---------------------------------------------------------------------------
// Layer 2 (O=10, one 16-wide n-tile, 16x16x32): R9-exact proven version.
__global__ __launch_bounds__(512, 2) void qgemm_small(
    const float* __restrict__ hIn, const _Float16* __restrict__ Wt,
    float* __restrict__ part2, const uint32_t* __restrict__ gtab) {
  __shared__ _Float16 hT[128 * 256];
  const int tid = threadIdx.x;
  const int l = tid & 63;
  const int wid = tid >> 6;
  const int kch = blockIdx.x & 7;
  const int rb = blockIdx.x >> 3;
  const int tbase = kch * TPC;

  {
    int r = tid >> 2, sg = tid & 3;
    const float* src = hIn + (size_t)(rb * 128 + r) * 256 + sg * 64;
    char* dst = (char*)hT + r * 512;
    int xo = (r & 7) << 4;
#pragma unroll
    for (int oc = 0; oc < 8; ++oc) {
      float4 f0 = *(const float4*)(src + oc * 8);
      float4 f1 = *(const float4*)(src + oc * 8 + 4);
      half8 hv;
      hv[0] = (_Float16)f0.x; hv[1] = (_Float16)f0.y;
      hv[2] = (_Float16)f0.z; hv[3] = (_Float16)f0.w;
      hv[4] = (_Float16)f1.x; hv[5] = (_Float16)f1.y;
      hv[6] = (_Float16)f1.z; hv[7] = (_Float16)f1.w;
      *(half8*)(dst + ((sg * 128 + oc * 16) ^ xo)) = hv;
    }
  }
  __syncthreads();

  floatx4 acc;
#pragma unroll
  for (int rg = 0; rg < 4; ++rg) acc[rg] = 0.f;

  const int rowb = (wid * 16 + (l & 15)) * 512;
  const int xorb = (l & 7) << 4;
  const int koffA = (l >> 4) * 16;
  const char* hTb = (const char*)hT;

  half8 a, sc;
  int prevjb;

  {
    uint32_t e0 = gtab[tbase];
    int jb = (int)(e0 & 0xFFFFu);
    a = *(const half8*)(hTb + rowb + ((jb * 2 + koffA) ^ xorb));
    half8 b = *(const half8*)(Wt + (size_t)tbase * 512 + l * 8);
    acc = mfma16(a, b, acc);
    prevjb = jb;
  }

  for (int u8 = 0; u8 < 18; ++u8) {
    uint32_t e = gtab[tbase + 1 + u8 * 8];
    int i0b = (int)(e >> 16);
    int jb = (int)(e & 0xFFFFu);
    const int ttb = tbase + 1 + u8 * 8;
    half8 bq[8];
#pragma unroll
    for (int s = 0; s < 8; ++s)
      bq[s] = *(const half8*)(Wt + (size_t)(ttb + s) * 512 + l * 8);
    if (jb != prevjb) {
      prevjb = jb;
      a = *(const half8*)(hTb + rowb + ((jb * 2 + koffA) ^ xorb));
    }
    sc = *(const half8*)(hTb + rowb + ((i0b * 2) ^ xorb));
#pragma unroll
    for (int s = 0; s < 8; ++s) {
      _Float16 sv = sc[s];
      half8 sb = {sv, sv, sv, sv, sv, sv, sv, sv};
      acc = mfma16(a * sb, bq[s], acc);
    }
  }

  float* op = part2 + (size_t)kch * 65536;
  const int r0 = rb * 128 + wid * 16 + (l >> 4) * 4;
  const int c = l & 15;
#pragma unroll
  for (int rg = 0; rg < 4; ++rg)
    op[(size_t)(r0 + rg) * 16 + c] = acc[rg];
}

// ---------------------------------------------------------------------------
extern "C" void kernel_launch(void* const* d_in, const int* in_sizes, int n_in,
                              void* d_out, int out_size, void* d_ws, size_t ws_size,
                              hipStream_t stream) {
  const float* x = (const float*)d_in[0];
  const float* W0 = (const float*)d_in[1];
  const float* b0 = (const float*)d_in[2];
  const float* W1 = (const float*)d_in[3];
  const float* b1 = (const float*)d_in[4];
  const float* W2 = (const float*)d_in[5];
  const float* b2 = (const float*)d_in[6];
  float* out = (float*)d_out;

  char* ws = (char*)d_ws;
  float* h1 = (float*)ws;                                  // 4 MB
  float* h2 = (float*)(ws + (4u << 20));                   // 4 MB
  _Float16* Wt = (_Float16*)(ws + (8u << 20));             // 19,005,440 B
  uint32_t* tab = (uint32_t*)(ws + (8u << 20) + 19005440u);
  float* part = (float*)(ws + (28u << 20));                // 8 x 4 MB partials
  float* part2 = part;                                     // reuse (2 MB)

  build_tab<<<(NTILES + 255) / 256, 256, 0, stream>>>(tab);

  // layer 0
  convert_w<<<(NTILES * 16 * 64) / 256, 256, 0, stream>>>(W0, Wt, tab, 16, 256);
  qgemm_main<<<256, 512, 0, stream>>>(x, Wt, part, tab);
  reduce_h<<<1024, 256, 0, stream>>>(part, b0, h1);
  // layer 1
  convert_w<<<(NTILES * 16 * 64) / 256, 256, 0, stream>>>(W1, Wt, tab, 16, 256);
  qgemm_main<<<256, 512, 0, stream>>>(h1, Wt, part, tab);
  reduce_h<<<1024, 256, 0, stream>>>(part, b1, h2);
  // layer 2
  convert_w<<<(NTILES * 1 * 64 + 255) / 256, 256, 0, stream>>>(W2, Wt, tab, 1, 10);
  qgemm_small<<<256, 512, 0, stream>>>(h2, Wt, part2, tab);
  reduce_out<<<160, 256, 0, stream>>>(part2, b2, out);
}